// Round 1
// baseline (1183.937 us; speedup 1.0000x reference)
//
#include <hip/hip_runtime.h>

#define F_IN 256
#define HID 128

// ---------------- graph preprocessing ----------------

__global__ void k_count(const int* __restrict__ col, int E, int* __restrict__ cnt) {
  int e = blockIdx.x * blockDim.x + threadIdx.x;
  if (e < E) atomicAdd(&cnt[col[e]], 1);
}

__global__ void k_scan_block(const int* __restrict__ in, int n, int* __restrict__ out,
                             int* __restrict__ bsum) {
  __shared__ int s[1024];
  int tid = threadIdx.x;
  int i = blockIdx.x * 1024 + tid;
  int v = (i < n) ? in[i] : 0;
  s[tid] = v;
  __syncthreads();
  for (int off = 1; off < 1024; off <<= 1) {
    int t = (tid >= off) ? s[tid - off] : 0;
    __syncthreads();
    s[tid] += t;
    __syncthreads();
  }
  if (i < n) out[i] = s[tid] - v;          // exclusive
  if (tid == 1023) bsum[blockIdx.x] = s[1023];
}

__global__ void k_scan_single(int* __restrict__ bsum, int nb, int* __restrict__ tail) {
  if (threadIdx.x == 0 && blockIdx.x == 0) {
    int run = 0;
    for (int b = 0; b < nb; ++b) { int t = bsum[b]; bsum[b] = run; run += t; }
    *tail = run;                            // offs[N] = total edges
  }
}

__global__ void k_add_off(int* __restrict__ out, const int* __restrict__ bsum, int n) {
  int i = blockIdx.x * blockDim.x + threadIdx.x;
  if (i < n) out[i] += bsum[i >> 10];
}

__global__ void k_scatter(const int* __restrict__ row, const int* __restrict__ col, int E,
                          const int* __restrict__ offs, int* __restrict__ cur,
                          int* __restrict__ csr) {
  int e = blockIdx.x * blockDim.x + threadIdx.x;
  if (e >= E) return;
  int c = col[e];
  int p = offs[c] + atomicAdd(&cur[c], 1);
  csr[p] = row[e];
}

// ---------------- dense GEMM: out = scale(node) * (x @ W^T + b) ----------------
// tile: 64 nodes x 128 cols, K-tile 32; 256 threads, each 4 nodes x 8 cols.

__global__ __launch_bounds__(256) void k_gemm(
    const float* __restrict__ x, const float* __restrict__ W, const float* __restrict__ bias,
    int n,
    const int* __restrict__ cnt1, float* __restrict__ out1,
    const int* __restrict__ cnt2, float* __restrict__ out2)
{
  __shared__ float xsT[32][64];    // [k][node]
  __shared__ float wsT[32][128];   // [k][col]
  int tid = threadIdx.x;
  int m0 = blockIdx.x * 64;
  int tx = tid & 15, ty = tid >> 4;      // tx -> col group (8 cols), ty -> node group (4 nodes)

  float acc[4][8];
#pragma unroll
  for (int j = 0; j < 8; ++j) {
    float bv = bias[tx * 8 + j];
#pragma unroll
    for (int i = 0; i < 4; ++i) acc[i][j] = bv;
  }

  for (int k0 = 0; k0 < F_IN; k0 += 32) {
    __syncthreads();
    // stage x tile (lane dim = node -> conflict-free LDS writes)
#pragma unroll
    for (int l = 0; l < 2; ++l) {
      int f = l * 256 + tid;
      int node = f & 63, kq = f >> 6;
      int gn = m0 + node;
      float4 v = make_float4(0.f, 0.f, 0.f, 0.f);
      if (gn < n) v = *(const float4*)(x + (size_t)gn * F_IN + k0 + kq * 4);
      xsT[kq * 4 + 0][node] = v.x; xsT[kq * 4 + 1][node] = v.y;
      xsT[kq * 4 + 2][node] = v.z; xsT[kq * 4 + 3][node] = v.w;
    }
    // stage W tile (lane dim = col)
#pragma unroll
    for (int l = 0; l < 4; ++l) {
      int f = l * 256 + tid;
      int c = f & 127, kq = f >> 7;
      float4 v = *(const float4*)(W + (size_t)c * F_IN + k0 + kq * 4);
      wsT[kq * 4 + 0][c] = v.x; wsT[kq * 4 + 1][c] = v.y;
      wsT[kq * 4 + 2][c] = v.z; wsT[kq * 4 + 3][c] = v.w;
    }
    __syncthreads();
#pragma unroll
    for (int kk = 0; kk < 32; ++kk) {
      float4 av = *(const float4*)&xsT[kk][ty * 4];
      float4 b0 = *(const float4*)&wsT[kk][tx * 8];
      float4 b1 = *(const float4*)&wsT[kk][tx * 8 + 4];
      float a[4] = {av.x, av.y, av.z, av.w};
      float bb[8] = {b0.x, b0.y, b0.z, b0.w, b1.x, b1.y, b1.z, b1.w};
#pragma unroll
      for (int i = 0; i < 4; ++i)
#pragma unroll
        for (int j = 0; j < 8; ++j) acc[i][j] += a[i] * bb[j];
    }
  }

#pragma unroll
  for (int i = 0; i < 4; ++i) {
    int gn = m0 + ty * 4 + i;
    if (gn >= n) continue;
    float s1 = rsqrtf((float)(cnt1[gn] + 1));
    float4 o0 = make_float4(acc[i][0] * s1, acc[i][1] * s1, acc[i][2] * s1, acc[i][3] * s1);
    float4 o1 = make_float4(acc[i][4] * s1, acc[i][5] * s1, acc[i][6] * s1, acc[i][7] * s1);
    float* dst = out1 + (size_t)gn * HID + tx * 8;
    *(float4*)dst = o0; *(float4*)(dst + 4) = o1;
    if (out2) {
      float s2 = rsqrtf((float)(cnt2[gn] + 1));
      float4 p0 = make_float4(acc[i][0] * s2, acc[i][1] * s2, acc[i][2] * s2, acc[i][3] * s2);
      float4 p1 = make_float4(acc[i][4] * s2, acc[i][5] * s2, acc[i][6] * s2, acc[i][7] * s2);
      float* dst2 = out2 + (size_t)gn * HID + tx * 8;
      *(float4*)dst2 = p0; *(float4*)(dst2 + 4) = p1;
    }
  }
}

// ---------------- SpMM: g'[i] = scale(i) * (g[i] + sum_{src in N(i)} g[src]) ----------------
// one wave per destination node; 64 lanes x float2 = 128 features.
// mode 0: scale = 1/deg (intermediate, stays in g-space)
// mode 1: scale = rsqrt(deg) (final, converts back to h-space)
// mode 2: mode 1 + add addsrc (fused z1 = z0 + knn-prop)

__global__ __launch_bounds__(256) void k_spmm(
    const float2* __restrict__ gin, float2* __restrict__ gout,
    const int* __restrict__ csr, const int* __restrict__ offs, const int* __restrict__ cnt,
    int n, int mode, const float2* __restrict__ addsrc)
{
  int w = (blockIdx.x << 2) | ((int)threadIdx.x >> 6);
  if (w >= n) return;
  int lane = threadIdx.x & 63;
  int beg = offs[w], end = offs[w + 1];
  size_t base = (size_t)w * 64 + lane;
  float2 acc = gin[base];                      // self loop
  int e = beg;
  for (; e + 4 <= end; e += 4) {
    int s0 = csr[e], s1 = csr[e + 1], s2 = csr[e + 2], s3 = csr[e + 3];
    float2 v0 = gin[(size_t)s0 * 64 + lane];
    float2 v1 = gin[(size_t)s1 * 64 + lane];
    float2 v2 = gin[(size_t)s2 * 64 + lane];
    float2 v3 = gin[(size_t)s3 * 64 + lane];
    acc.x += v0.x + v1.x + v2.x + v3.x;
    acc.y += v0.y + v1.y + v2.y + v3.y;
  }
  for (; e < end; ++e) {
    int s0 = csr[e];
    float2 v = gin[(size_t)s0 * 64 + lane];
    acc.x += v.x; acc.y += v.y;
  }
  float deg = (float)(cnt[w] + 1);
  float2 o;
  if (mode == 0) {
    float sc = 1.0f / deg;
    o.x = acc.x * sc; o.y = acc.y * sc;
  } else {
    float sc = rsqrtf(deg);
    o.x = acc.x * sc; o.y = acc.y * sc;
    if (mode == 2) { float2 z = addsrc[base]; o.x += z.x; o.y += z.y; }
  }
  gout[base] = o;
}

// ---------------- launch ----------------

extern "C" void kernel_launch(void* const* d_in, const int* in_sizes, int n_in,
                              void* d_out, int out_size, void* d_ws, size_t ws_size,
                              hipStream_t stream) {
  const float* x    = (const float*)d_in[0];
  const int*   ei   = (const int*)d_in[1];
  const int*   knn  = (const int*)d_in[2];
  const float* W_s1 = (const float*)d_in[3];
  const float* b_s1 = (const float*)d_in[4];
  const float* W_s2 = (const float*)d_in[5];
  const float* b_s2 = (const float*)d_in[6];
  const float* W_f2 = (const float*)d_in[7];
  const float* b_f2 = (const float*)d_in[8];

  const int N  = in_sizes[0] / F_IN;
  const int E  = in_sizes[1] / 2;
  const int EK = in_sizes[2] / 2;
  const int* row_s = ei;       const int* col_s = ei + E;
  const int* row_k = knn;      const int* col_k = knn + EK;

  char* p = (char*)d_ws;
  auto carve = [&](size_t bytes) {
    char* r = p; p += (bytes + 511) & ~(size_t)511; return (void*)r;
  };
  int* cnt_s = (int*)carve((size_t)N * 4);
  int* cnt_k = (int*)carve((size_t)N * 4);
  int* cur_s = (int*)carve((size_t)N * 4);
  int* cur_k = (int*)carve((size_t)N * 4);
  char* zero_end = p;
  int* offs_s = (int*)carve((size_t)(N + 1) * 4);
  int* offs_k = (int*)carve((size_t)(N + 1) * 4);
  int* bsum   = (int*)carve(4096);
  int* csr_s  = (int*)carve((size_t)E * 4);
  int* csr_k  = (int*)carve((size_t)EK * 4);
  float* gA = (float*)carve((size_t)N * HID * 4);
  float* gB = (float*)carve((size_t)N * HID * 4);
  float* gK = (float*)carve((size_t)N * HID * 4);

  float* out_h0 = (float*)d_out;
  float* out_h1 = out_h0 + (size_t)N * HID;
  float* out_z0 = out_h1 + (size_t)N * HID;
  float* out_z1 = out_z0 + (size_t)N * HID;

  hipMemsetAsync(d_ws, 0, (size_t)(zero_end - (char*)d_ws), stream);

  const int tpb = 256;
  k_count<<<(E + tpb - 1) / tpb, tpb, 0, stream>>>(col_s, E, cnt_s);
  k_count<<<(EK + tpb - 1) / tpb, tpb, 0, stream>>>(col_k, EK, cnt_k);

  int nb = (N + 1023) / 1024;
  k_scan_block<<<nb, 1024, 0, stream>>>(cnt_s, N, offs_s, bsum);
  k_scan_single<<<1, 64, 0, stream>>>(bsum, nb, offs_s + N);
  k_add_off<<<(N + tpb - 1) / tpb, tpb, 0, stream>>>(offs_s, bsum, N);
  k_scan_block<<<nb, 1024, 0, stream>>>(cnt_k, N, offs_k, bsum);
  k_scan_single<<<1, 64, 0, stream>>>(bsum, nb, offs_k + N);
  k_add_off<<<(N + tpb - 1) / tpb, tpb, 0, stream>>>(offs_k, bsum, N);

  k_scatter<<<(E + tpb - 1) / tpb, tpb, 0, stream>>>(row_s, col_s, E, offs_s, cur_s, csr_s);
  k_scatter<<<(EK + tpb - 1) / tpb, tpb, 0, stream>>>(row_k, col_k, EK, offs_k, cur_k, csr_k);

  int gemm_grid = (N + 63) / 64;
  int spmm_grid = (N + 3) / 4;

  // chain s1: K=2
  k_gemm<<<gemm_grid, 256, 0, stream>>>(x, W_s1, b_s1, N, cnt_s, gA, nullptr, nullptr);
  k_spmm<<<spmm_grid, 256, 0, stream>>>((const float2*)gA, (float2*)gB, csr_s, offs_s, cnt_s, N, 0, nullptr);
  k_spmm<<<spmm_grid, 256, 0, stream>>>((const float2*)gB, (float2*)out_h0, csr_s, offs_s, cnt_s, N, 1, nullptr);

  // chain s2: K=10
  k_gemm<<<gemm_grid, 256, 0, stream>>>(x, W_s2, b_s2, N, cnt_s, gA, nullptr, nullptr);
  {
    float* src = gA; float* dst = gB;
    for (int it = 0; it < 9; ++it) {
      k_spmm<<<spmm_grid, 256, 0, stream>>>((const float2*)src, (float2*)dst, csr_s, offs_s, cnt_s, N, 0, nullptr);
      float* t = src; src = dst; dst = t;
    }
    k_spmm<<<spmm_grid, 256, 0, stream>>>((const float2*)src, (float2*)out_h1, csr_s, offs_s, cnt_s, N, 1, nullptr);
  }

  // chain f2: K=2 structural (z0) + K=1 knn (z1), sharing the GEMM
  k_gemm<<<gemm_grid, 256, 0, stream>>>(x, W_f2, b_f2, N, cnt_s, gA, cnt_k, gK);
  k_spmm<<<spmm_grid, 256, 0, stream>>>((const float2*)gA, (float2*)gB, csr_s, offs_s, cnt_s, N, 0, nullptr);
  k_spmm<<<spmm_grid, 256, 0, stream>>>((const float2*)gB, (float2*)out_z0, csr_s, offs_s, cnt_s, N, 1, nullptr);
  k_spmm<<<spmm_grid, 256, 0, stream>>>((const float2*)gK, (float2*)out_z1, csr_k, offs_k, cnt_k, N, 2, (const float2*)out_z0);
}

// Round 2
// 784.187 us; speedup vs baseline: 1.5098x; 1.5098x over previous
//
#include <hip/hip_runtime.h>
#include <hip/hip_fp16.h>

#define F_IN 256
#define HID 128

typedef _Float16 half8 __attribute__((ext_vector_type(8)));
typedef _Float16 half4v __attribute__((ext_vector_type(4)));
typedef float f32x4 __attribute__((ext_vector_type(4)));

// ---------------- graph preprocessing ----------------

__global__ void k_count(const int* __restrict__ col, int E, int* __restrict__ cnt) {
  int e = blockIdx.x * blockDim.x + threadIdx.x;
  if (e < E) atomicAdd(&cnt[col[e]], 1);
}

__global__ void k_scan_block(const int* __restrict__ in, int n, int* __restrict__ out,
                             int* __restrict__ bsum) {
  __shared__ int s[1024];
  int tid = threadIdx.x;
  int i = blockIdx.x * 1024 + tid;
  int v = (i < n) ? in[i] : 0;
  s[tid] = v;
  __syncthreads();
  for (int off = 1; off < 1024; off <<= 1) {
    int t = (tid >= off) ? s[tid - off] : 0;
    __syncthreads();
    s[tid] += t;
    __syncthreads();
  }
  if (i < n) out[i] = s[tid] - v;          // exclusive
  if (tid == 1023) bsum[blockIdx.x] = s[1023];
}

__global__ void k_scan_single(int* __restrict__ bsum, int nb, int* __restrict__ tail) {
  if (threadIdx.x == 0 && blockIdx.x == 0) {
    int run = 0;
    for (int b = 0; b < nb; ++b) { int t = bsum[b]; bsum[b] = run; run += t; }
    *tail = run;
  }
}

__global__ void k_add_off(int* __restrict__ out, const int* __restrict__ bsum, int n) {
  int i = blockIdx.x * blockDim.x + threadIdx.x;
  if (i < n) out[i] += bsum[i >> 10];
}

__global__ void k_scatter(const int* __restrict__ row, const int* __restrict__ col, int E,
                          const int* __restrict__ offs, int* __restrict__ cur,
                          int* __restrict__ csr) {
  int e = blockIdx.x * blockDim.x + threadIdx.x;
  if (e >= E) return;
  int c = col[e];
  int p = offs[c] + atomicAdd(&cur[c], 1);
  csr[p] = row[e];
}

// ---------------- W fp32 -> fp16 (all three, concatenated) ----------------

__global__ void k_cvt_w(const float* __restrict__ W0, const float* __restrict__ W1,
                        const float* __restrict__ W2, _Float16* __restrict__ Wh) {
  const int sz = HID * F_IN;                    // 32768
  int idx = (blockIdx.x * 256 + threadIdx.x) * 4;  // [0, 3*sz)
  const float* src = (idx < sz) ? (W0 + idx)
                   : (idx < 2 * sz) ? (W1 + idx - sz)
                   : (W2 + idx - 2 * sz);
  float4 v = *(const float4*)src;
  half4v o;
  o[0] = (_Float16)v.x; o[1] = (_Float16)v.y; o[2] = (_Float16)v.z; o[3] = (_Float16)v.w;
  *(half4v*)(Wh + idx) = o;
}

// ---------------- fused MFMA GEMM: 3 weights, 4 scaled fp16 outputs ----------------
// out[w] = rsqrt(deg) * (x @ W[w]^T + b[w]); f2 written with both deg_s and deg_k scales.
// Per wave: 16 nodes. mfma(W_frag, x_frag): D rows (regs) = HID cols, D cols (lane&15) = node.

__global__ __launch_bounds__(256) void k_gemm3(
    const float* __restrict__ x, const _Float16* __restrict__ Wh,
    const float* __restrict__ b0, const float* __restrict__ b1, const float* __restrict__ b2,
    int n, const int* __restrict__ cnt_s, const int* __restrict__ cnt_k,
    _Float16* __restrict__ gS1, _Float16* __restrict__ gS2,
    _Float16* __restrict__ gF2s, _Float16* __restrict__ gF2k)
{
  int lane = threadIdx.x & 63;
  int wv = threadIdx.x >> 6;
  int l15 = lane & 15, lhi = lane >> 4;
  int mrow = blockIdx.x * 64 + wv * 16 + l15;
  bool mok = mrow < n;

  // A fragments: entire 256-wide x row strip for this wave's 16 nodes, fp32->fp16
  half8 a[8];
  {
    const float* xr = x + (size_t)mrow * F_IN;
#pragma unroll
    for (int kt = 0; kt < 8; ++kt) {
      float4 lo = make_float4(0.f, 0.f, 0.f, 0.f), hi = lo;
      if (mok) {
        lo = *(const float4*)(xr + kt * 32 + lhi * 8);
        hi = *(const float4*)(xr + kt * 32 + lhi * 8 + 4);
      }
      half8 v;
      v[0] = (_Float16)lo.x; v[1] = (_Float16)lo.y; v[2] = (_Float16)lo.z; v[3] = (_Float16)lo.w;
      v[4] = (_Float16)hi.x; v[5] = (_Float16)hi.y; v[6] = (_Float16)hi.z; v[7] = (_Float16)hi.w;
      a[kt] = v;
    }
  }

  float ss = 1.0f, sk = 1.0f;
  if (mok) {
    ss = rsqrtf((float)(cnt_s[mrow] + 1));
    sk = rsqrtf((float)(cnt_k[mrow] + 1));
  }

#pragma unroll
  for (int w = 0; w < 3; ++w) {
    const _Float16* Wp = Wh + (size_t)w * HID * F_IN;
    const float* bias = (w == 0) ? b0 : (w == 1) ? b1 : b2;
    _Float16* dst = (w == 0) ? gS1 : (w == 1) ? gS2 : gF2s;
    for (int nt = 0; nt < 8; ++nt) {
      const _Float16* wrow = Wp + (size_t)(nt * 16 + l15) * F_IN;
      int nbase = nt * 16 + lhi * 4;
      float4 bv = *(const float4*)(bias + nbase);
      f32x4 acc = {bv.x, bv.y, bv.z, bv.w};
#pragma unroll
      for (int kt = 0; kt < 8; ++kt) {
        half8 bf = *(const half8*)(wrow + kt * 32 + lhi * 8);
        acc = __builtin_amdgcn_mfma_f32_16x16x32_f16(bf, a[kt], acc, 0, 0, 0);
      }
      if (mok) {
        half4v o;
        o[0] = (_Float16)(acc[0] * ss); o[1] = (_Float16)(acc[1] * ss);
        o[2] = (_Float16)(acc[2] * ss); o[3] = (_Float16)(acc[3] * ss);
        *(half4v*)(dst + (size_t)mrow * HID + nbase) = o;
        if (w == 2) {
          half4v o2;
          o2[0] = (_Float16)(acc[0] * sk); o2[1] = (_Float16)(acc[1] * sk);
          o2[2] = (_Float16)(acc[2] * sk); o2[3] = (_Float16)(acc[3] * sk);
          *(half4v*)(gF2k + (size_t)mrow * HID + nbase) = o2;
        }
      }
    }
  }
}

// ---------------- SpMM (fp16 features) ----------------
// g'[i] = scale(i) * (g[i] + sum_src g[src]);  one wave per dest node, 1 dword/lane.
// mode 0: *1/deg -> fp16 out;  mode 1: *rsqrt(deg) -> fp32 out;  mode 2: mode1 + addsrc.

__device__ inline float2 h2f2(unsigned int u) {
  __half2 h; *(unsigned int*)&h = u; return __half22float2(h);
}

__device__ inline void spmm_store(void* out, size_t base, float2 acc, float deg, int mode,
                                  const float2* __restrict__ add) {
  if (mode == 0) {
    float sc = 1.0f / deg;
    __half2 h = __float22half2_rn(make_float2(acc.x * sc, acc.y * sc));
    ((__half2*)out)[base] = h;
  } else {
    float sc = rsqrtf(deg);
    float2 o = make_float2(acc.x * sc, acc.y * sc);
    if (mode == 2) { float2 z = add[base]; o.x += z.x; o.y += z.y; }
    ((float2*)out)[base] = o;
  }
}

__global__ __launch_bounds__(256) void k_spmm_h(
    const unsigned int* __restrict__ gin, void* __restrict__ gout,
    const int* __restrict__ csr, const int* __restrict__ offs, const int* __restrict__ cnt,
    int n, int mode, const float2* __restrict__ addsrc)
{
  int w = (blockIdx.x << 2) | ((int)threadIdx.x >> 6);
  if (w >= n) return;
  int lane = threadIdx.x & 63;
  int beg = offs[w], end = offs[w + 1];
  size_t base = (size_t)w * 64 + lane;
  float2 acc = h2f2(gin[base]);                  // self loop
  int e = beg;
  for (; e + 4 <= end; e += 4) {
    unsigned int u0 = gin[(size_t)csr[e]     * 64 + lane];
    unsigned int u1 = gin[(size_t)csr[e + 1] * 64 + lane];
    unsigned int u2 = gin[(size_t)csr[e + 2] * 64 + lane];
    unsigned int u3 = gin[(size_t)csr[e + 3] * 64 + lane];
    float2 v0 = h2f2(u0), v1 = h2f2(u1), v2 = h2f2(u2), v3 = h2f2(u3);
    acc.x += v0.x + v1.x + v2.x + v3.x;
    acc.y += v0.y + v1.y + v2.y + v3.y;
  }
  for (; e < end; ++e) {
    float2 v = h2f2(gin[(size_t)csr[e] * 64 + lane]);
    acc.x += v.x; acc.y += v.y;
  }
  spmm_store(gout, base, acc, (float)(cnt[w] + 1), mode, addsrc);
}

// 3 feature matrices propagated in one pass over the graph (shared steps 1,2)
__global__ __launch_bounds__(256) void k_spmm3(
    const unsigned int* __restrict__ g0, const unsigned int* __restrict__ g1,
    const unsigned int* __restrict__ g2,
    void* __restrict__ o0, void* __restrict__ o1, void* __restrict__ o2,
    int md0, int md1, int md2,
    const int* __restrict__ csr, const int* __restrict__ offs, const int* __restrict__ cnt,
    int n)
{
  int w = (blockIdx.x << 2) | ((int)threadIdx.x >> 6);
  if (w >= n) return;
  int lane = threadIdx.x & 63;
  int beg = offs[w], end = offs[w + 1];
  size_t base = (size_t)w * 64 + lane;
  float2 a0 = h2f2(g0[base]), a1 = h2f2(g1[base]), a2 = h2f2(g2[base]);
  int e = beg;
  for (; e + 2 <= end; e += 2) {
    size_t s0 = (size_t)csr[e] * 64 + lane;
    size_t s1 = (size_t)csr[e + 1] * 64 + lane;
    unsigned int u00 = g0[s0], u01 = g1[s0], u02 = g2[s0];
    unsigned int u10 = g0[s1], u11 = g1[s1], u12 = g2[s1];
    float2 v;
    v = h2f2(u00); a0.x += v.x; a0.y += v.y;
    v = h2f2(u01); a1.x += v.x; a1.y += v.y;
    v = h2f2(u02); a2.x += v.x; a2.y += v.y;
    v = h2f2(u10); a0.x += v.x; a0.y += v.y;
    v = h2f2(u11); a1.x += v.x; a1.y += v.y;
    v = h2f2(u12); a2.x += v.x; a2.y += v.y;
  }
  for (; e < end; ++e) {
    size_t s0 = (size_t)csr[e] * 64 + lane;
    float2 v;
    v = h2f2(g0[s0]); a0.x += v.x; a0.y += v.y;
    v = h2f2(g1[s0]); a1.x += v.x; a1.y += v.y;
    v = h2f2(g2[s0]); a2.x += v.x; a2.y += v.y;
  }
  float deg = (float)(cnt[w] + 1);
  spmm_store(o0, base, a0, deg, md0, nullptr);
  spmm_store(o1, base, a1, deg, md1, nullptr);
  spmm_store(o2, base, a2, deg, md2, nullptr);
}

// ---------------- launch ----------------

extern "C" void kernel_launch(void* const* d_in, const int* in_sizes, int n_in,
                              void* d_out, int out_size, void* d_ws, size_t ws_size,
                              hipStream_t stream) {
  const float* x    = (const float*)d_in[0];
  const int*   ei   = (const int*)d_in[1];
  const int*   knn  = (const int*)d_in[2];
  const float* W_s1 = (const float*)d_in[3];
  const float* b_s1 = (const float*)d_in[4];
  const float* W_s2 = (const float*)d_in[5];
  const float* b_s2 = (const float*)d_in[6];
  const float* W_f2 = (const float*)d_in[7];
  const float* b_f2 = (const float*)d_in[8];

  const int N  = in_sizes[0] / F_IN;
  const int E  = in_sizes[1] / 2;
  const int EK = in_sizes[2] / 2;
  const int* row_s = ei;   const int* col_s = ei + E;
  const int* row_k = knn;  const int* col_k = knn + EK;

  char* p = (char*)d_ws;
  auto carve = [&](size_t bytes) {
    char* r = p; p += (bytes + 511) & ~(size_t)511; return (void*)r;
  };
  int* cnt_s = (int*)carve((size_t)N * 4);
  int* cnt_k = (int*)carve((size_t)N * 4);
  int* cur_s = (int*)carve((size_t)N * 4);
  int* cur_k = (int*)carve((size_t)N * 4);
  char* zero_end = p;
  int* offs_s = (int*)carve((size_t)(N + 1) * 4);
  int* offs_k = (int*)carve((size_t)(N + 1) * 4);
  int* bsum   = (int*)carve(4096);
  int* csr_s  = (int*)carve((size_t)E * 4);
  int* csr_k  = (int*)carve((size_t)EK * 4);
  _Float16* Wh  = (_Float16*)carve((size_t)3 * HID * F_IN * 2);
  _Float16* gS1 = (_Float16*)carve((size_t)N * HID * 2);
  _Float16* gS2 = (_Float16*)carve((size_t)N * HID * 2);
  _Float16* gF2s= (_Float16*)carve((size_t)N * HID * 2);
  _Float16* gF2k= (_Float16*)carve((size_t)N * HID * 2);
  _Float16* tS2 = (_Float16*)carve((size_t)N * HID * 2);

  float* out_h0 = (float*)d_out;
  float* out_h1 = out_h0 + (size_t)N * HID;
  float* out_z0 = out_h1 + (size_t)N * HID;
  float* out_z1 = out_z0 + (size_t)N * HID;
  // z1 region (fp32, N*HID floats = 2x fp16 buffers) is free until the very last
  // launch -> use it as scratch for the two single-use step-1 outputs.
  _Float16* tS1 = (_Float16*)out_z1;
  _Float16* tF2 = tS1 + (size_t)N * HID;

  hipMemsetAsync(d_ws, 0, (size_t)(zero_end - (char*)d_ws), stream);

  const int tpb = 256;
  k_count<<<(E + tpb - 1) / tpb, tpb, 0, stream>>>(col_s, E, cnt_s);
  k_count<<<(EK + tpb - 1) / tpb, tpb, 0, stream>>>(col_k, EK, cnt_k);

  int nb = (N + 1023) / 1024;
  k_scan_block<<<nb, 1024, 0, stream>>>(cnt_s, N, offs_s, bsum);
  k_scan_single<<<1, 64, 0, stream>>>(bsum, nb, offs_s + N);
  k_add_off<<<(N + tpb - 1) / tpb, tpb, 0, stream>>>(offs_s, bsum, N);
  k_scan_block<<<nb, 1024, 0, stream>>>(cnt_k, N, offs_k, bsum);
  k_scan_single<<<1, 64, 0, stream>>>(bsum, nb, offs_k + N);
  k_add_off<<<(N + tpb - 1) / tpb, tpb, 0, stream>>>(offs_k, bsum, N);

  k_scatter<<<(E + tpb - 1) / tpb, tpb, 0, stream>>>(row_s, col_s, E, offs_s, cur_s, csr_s);
  k_scatter<<<(EK + tpb - 1) / tpb, tpb, 0, stream>>>(row_k, col_k, EK, offs_k, cur_k, csr_k);

  k_cvt_w<<<96, 256, 0, stream>>>(W_s1, W_s2, W_f2, Wh);
  k_gemm3<<<(N + 63) / 64, 256, 0, stream>>>(x, Wh, b_s1, b_s2, b_f2, N, cnt_s, cnt_k,
                                             gS1, gS2, gF2s, gF2k);

  int spmm_grid = (N + 3) / 4;

  // step 1 (all chains), step 2 (s1 & f2 finalize, s2 continues)
  k_spmm3<<<spmm_grid, 256, 0, stream>>>((const unsigned int*)gS1, (const unsigned int*)gS2,
                                         (const unsigned int*)gF2s,
                                         tS1, tS2, tF2, 0, 0, 0,
                                         csr_s, offs_s, cnt_s, N);
  k_spmm3<<<spmm_grid, 256, 0, stream>>>((const unsigned int*)tS1, (const unsigned int*)tS2,
                                         (const unsigned int*)tF2,
                                         out_h0, gS1, out_z0, 1, 0, 1,
                                         csr_s, offs_s, cnt_s, N);

  // s2 steps 3..10: ping-pong gS1 <-> tS2 (both free for reuse now)
  {
    _Float16* cur = gS1; _Float16* alt = tS2;
    for (int it = 0; it < 7; ++it) {
      k_spmm_h<<<spmm_grid, 256, 0, stream>>>((const unsigned int*)cur, alt,
                                              csr_s, offs_s, cnt_s, N, 0, nullptr);
      _Float16* t = cur; cur = alt; alt = t;
    }
    k_spmm_h<<<spmm_grid, 256, 0, stream>>>((const unsigned int*)cur, out_h1,
                                            csr_s, offs_s, cnt_s, N, 1, nullptr);
  }

  // knn step (last: frees the z1 scratch region before writing it)
  k_spmm_h<<<spmm_grid, 256, 0, stream>>>((const unsigned int*)gF2k, out_z1,
                                          csr_k, offs_k, cnt_k, N, 2,
                                          (const float2*)out_z0);
}

// Round 3
// 737.020 us; speedup vs baseline: 1.6064x; 1.0640x over previous
//
#include <hip/hip_runtime.h>
#include <hip/hip_fp16.h>

#define F_IN 256
#define HID 128

typedef _Float16 half8 __attribute__((ext_vector_type(8)));
typedef _Float16 half4v __attribute__((ext_vector_type(4)));
typedef float f32x4 __attribute__((ext_vector_type(4)));

// ---------------- graph preprocessing ----------------

__global__ void k_count2(const int* __restrict__ col_s, int E, int* __restrict__ cnt_s,
                         const int* __restrict__ col_k, int EK, int* __restrict__ cnt_k) {
  int e = blockIdx.x * blockDim.x + threadIdx.x;
  if (e < E) {
    atomicAdd(&cnt_s[col_s[e]], 1);
  } else {
    int f = e - E;
    if (f < EK) atomicAdd(&cnt_k[col_k[f]], 1);
  }
}

__global__ void k_scan_block(const int* __restrict__ in, int n, int* __restrict__ out,
                             int* __restrict__ bsum) {
  __shared__ int s[1024];
  int tid = threadIdx.x;
  int i = blockIdx.x * 1024 + tid;
  int v = (i < n) ? in[i] : 0;
  s[tid] = v;
  __syncthreads();
  for (int off = 1; off < 1024; off <<= 1) {
    int t = (tid >= off) ? s[tid - off] : 0;
    __syncthreads();
    s[tid] += t;
    __syncthreads();
  }
  if (i < n) out[i] = s[tid] - v;          // exclusive
  if (tid == 1023) bsum[blockIdx.x] = s[1023];
}

__global__ void k_scan_single(int* __restrict__ bsum, int nb, int* __restrict__ tail) {
  if (threadIdx.x == 0 && blockIdx.x == 0) {
    int run = 0;
    for (int b = 0; b < nb; ++b) { int t = bsum[b]; bsum[b] = run; run += t; }
    *tail = run;
  }
}

__global__ void k_add_off(int* __restrict__ out, const int* __restrict__ bsum, int n) {
  int i = blockIdx.x * blockDim.x + threadIdx.x;
  if (i < n) out[i] += bsum[i >> 10];
}

__global__ void k_scatter2(const int* __restrict__ row_s, const int* __restrict__ col_s, int E,
                           const int* __restrict__ offs_s, int* __restrict__ cur_s,
                           int* __restrict__ csr_s,
                           const int* __restrict__ row_k, const int* __restrict__ col_k, int EK,
                           const int* __restrict__ offs_k, int* __restrict__ cur_k,
                           int* __restrict__ csr_k) {
  int e = blockIdx.x * blockDim.x + threadIdx.x;
  if (e < E) {
    int c = col_s[e];
    int p = offs_s[c] + atomicAdd(&cur_s[c], 1);
    csr_s[p] = row_s[e];
  } else {
    int f = e - E;
    if (f < EK) {
      int c = col_k[f];
      int p = offs_k[c] + atomicAdd(&cur_k[c], 1);
      csr_k[p] = row_k[f];
    }
  }
}

// ---------------- W fp32 -> fp16 (all three, concatenated) ----------------

__global__ void k_cvt_w(const float* __restrict__ W0, const float* __restrict__ W1,
                        const float* __restrict__ W2, _Float16* __restrict__ Wh) {
  const int sz = HID * F_IN;                    // 32768
  int idx = (blockIdx.x * 256 + threadIdx.x) * 4;  // [0, 3*sz)
  const float* src = (idx < sz) ? (W0 + idx)
                   : (idx < 2 * sz) ? (W1 + idx - sz)
                   : (W2 + idx - 2 * sz);
  float4 v = *(const float4*)src;
  half4v o;
  o[0] = (_Float16)v.x; o[1] = (_Float16)v.y; o[2] = (_Float16)v.z; o[3] = (_Float16)v.w;
  *(half4v*)(Wh + idx) = o;
}

// ---------------- fused MFMA GEMM ----------------
// grid (tiles, 3): blockIdx.y selects the weight matrix. 64 nodes per block,
// 16 per wave. x fragments held resident in VGPRs (launch_bounds 4 -> 128 cap).

__global__ __launch_bounds__(256, 4) void k_gemm3(
    const float* __restrict__ x, const _Float16* __restrict__ Wh,
    const float* __restrict__ b0, const float* __restrict__ b1, const float* __restrict__ b2,
    int n, const int* __restrict__ cnt_s, const int* __restrict__ cnt_k,
    _Float16* __restrict__ gS1, _Float16* __restrict__ gS2,
    _Float16* __restrict__ gF2s, _Float16* __restrict__ gF2k)
{
  int w = blockIdx.y;
  int lane = threadIdx.x & 63;
  int wv = threadIdx.x >> 6;
  int l15 = lane & 15, lhi = lane >> 4;
  int mrow = blockIdx.x * 64 + wv * 16 + l15;
  bool mok = mrow < n;
  int arow = mok ? mrow : (n - 1);

  // A fragments: 256-wide x row strip, fp32->fp16, kept in registers
  half8 a[8];
  {
    const float* xr = x + (size_t)arow * F_IN;
#pragma unroll
    for (int kt = 0; kt < 8; ++kt) {
      float4 lo = *(const float4*)(xr + kt * 32 + lhi * 8);
      float4 hi = *(const float4*)(xr + kt * 32 + lhi * 8 + 4);
      half8 v;
      v[0] = (_Float16)lo.x; v[1] = (_Float16)lo.y; v[2] = (_Float16)lo.z; v[3] = (_Float16)lo.w;
      v[4] = (_Float16)hi.x; v[5] = (_Float16)hi.y; v[6] = (_Float16)hi.z; v[7] = (_Float16)hi.w;
      a[kt] = v;
    }
  }
#pragma unroll
  for (int kt = 0; kt < 8; ++kt) asm volatile("" :: "v"(a[kt]));  // keep resident

  float ss = rsqrtf((float)(cnt_s[arow] + 1));
  float sk = (w == 2) ? rsqrtf((float)(cnt_k[arow] + 1)) : 0.f;
  const float* bias = (w == 0) ? b0 : (w == 1) ? b1 : b2;
  _Float16* dst = (w == 0) ? gS1 : (w == 1) ? gS2 : gF2s;
  const _Float16* Wp = Wh + (size_t)w * HID * F_IN;

#pragma unroll
  for (int nt = 0; nt < 8; ++nt) {
    const _Float16* wrow = Wp + (size_t)(nt * 16 + l15) * F_IN;
    int nbase = nt * 16 + lhi * 4;
    float4 bv = *(const float4*)(bias + nbase);
    f32x4 acc = {bv.x, bv.y, bv.z, bv.w};
#pragma unroll
    for (int kt = 0; kt < 8; ++kt) {
      half8 bf = *(const half8*)(wrow + kt * 32 + lhi * 8);
      acc = __builtin_amdgcn_mfma_f32_16x16x32_f16(bf, a[kt], acc, 0, 0, 0);
    }
    if (mok) {
      half4v o;
      o[0] = (_Float16)(acc[0] * ss); o[1] = (_Float16)(acc[1] * ss);
      o[2] = (_Float16)(acc[2] * ss); o[3] = (_Float16)(acc[3] * ss);
      *(half4v*)(dst + (size_t)mrow * HID + nbase) = o;
      if (w == 2) {
        half4v o2;
        o2[0] = (_Float16)(acc[0] * sk); o2[1] = (_Float16)(acc[1] * sk);
        o2[2] = (_Float16)(acc[2] * sk); o2[3] = (_Float16)(acc[3] * sk);
        *(half4v*)(gF2k + (size_t)mrow * HID + nbase) = o2;
      }
    }
  }
}

// ---------------- SpMM (fp16 features) ----------------
// g'[i] = scale(i) * (g[i] + sum_src g[src]);  one wave per dest node, 1 dword/lane.
// mode 0: *1/deg -> fp16 out;  mode 1: *rsqrt(deg) -> fp32 out;  mode 2: mode1 + addsrc.

__device__ inline float2 h2f2(unsigned int u) {
  __half2 h; *(unsigned int*)&h = u; return __half22float2(h);
}

__device__ inline void spmm_store(void* out, size_t base, float2 acc, float deg, int mode,
                                  const float2* __restrict__ add) {
  if (mode == 0) {
    float sc = 1.0f / deg;
    __half2 h = __float22half2_rn(make_float2(acc.x * sc, acc.y * sc));
    ((__half2*)out)[base] = h;
  } else {
    float sc = rsqrtf(deg);
    float2 o = make_float2(acc.x * sc, acc.y * sc);
    if (mode == 2) { float2 z = add[base]; o.x += z.x; o.y += z.y; }
    ((float2*)out)[base] = o;
  }
}

__global__ __launch_bounds__(256) void k_spmm_h(
    const unsigned int* __restrict__ gin, void* __restrict__ gout,
    const int* __restrict__ csr, const int* __restrict__ offs, const int* __restrict__ cnt,
    int n, int mode, const float2* __restrict__ addsrc)
{
  int w = (blockIdx.x << 2) | ((int)threadIdx.x >> 6);
  if (w >= n) return;
  int lane = threadIdx.x & 63;
  int beg = offs[w], end = offs[w + 1];
  size_t base = (size_t)w * 64 + lane;
  float2 acc = h2f2(gin[base]);                  // self loop
  int e = beg;
  for (; e + 8 <= end; e += 8) {
    unsigned int u0 = gin[(size_t)csr[e]     * 64 + lane];
    unsigned int u1 = gin[(size_t)csr[e + 1] * 64 + lane];
    unsigned int u2 = gin[(size_t)csr[e + 2] * 64 + lane];
    unsigned int u3 = gin[(size_t)csr[e + 3] * 64 + lane];
    unsigned int u4 = gin[(size_t)csr[e + 4] * 64 + lane];
    unsigned int u5 = gin[(size_t)csr[e + 5] * 64 + lane];
    unsigned int u6 = gin[(size_t)csr[e + 6] * 64 + lane];
    unsigned int u7 = gin[(size_t)csr[e + 7] * 64 + lane];
    float2 v0 = h2f2(u0), v1 = h2f2(u1), v2 = h2f2(u2), v3 = h2f2(u3);
    float2 v4 = h2f2(u4), v5 = h2f2(u5), v6 = h2f2(u6), v7 = h2f2(u7);
    acc.x += (v0.x + v1.x) + (v2.x + v3.x) + ((v4.x + v5.x) + (v6.x + v7.x));
    acc.y += (v0.y + v1.y) + (v2.y + v3.y) + ((v4.y + v5.y) + (v6.y + v7.y));
  }
  for (; e + 2 <= end; e += 2) {
    unsigned int u0 = gin[(size_t)csr[e]     * 64 + lane];
    unsigned int u1 = gin[(size_t)csr[e + 1] * 64 + lane];
    float2 v0 = h2f2(u0), v1 = h2f2(u1);
    acc.x += v0.x + v1.x;
    acc.y += v0.y + v1.y;
  }
  if (e < end) {
    float2 v = h2f2(gin[(size_t)csr[e] * 64 + lane]);
    acc.x += v.x; acc.y += v.y;
  }
  spmm_store(gout, base, acc, (float)(cnt[w] + 1), mode, addsrc);
}

// 3 feature matrices propagated in one pass over the graph (shared steps 1,2)
__global__ __launch_bounds__(256) void k_spmm3(
    const unsigned int* __restrict__ g0, const unsigned int* __restrict__ g1,
    const unsigned int* __restrict__ g2,
    void* __restrict__ o0, void* __restrict__ o1, void* __restrict__ o2,
    int md0, int md1, int md2,
    const int* __restrict__ csr, const int* __restrict__ offs, const int* __restrict__ cnt,
    int n)
{
  int w = (blockIdx.x << 2) | ((int)threadIdx.x >> 6);
  if (w >= n) return;
  int lane = threadIdx.x & 63;
  int beg = offs[w], end = offs[w + 1];
  size_t base = (size_t)w * 64 + lane;
  float2 a0 = h2f2(g0[base]), a1 = h2f2(g1[base]), a2 = h2f2(g2[base]);
  int e = beg;
  for (; e + 2 <= end; e += 2) {
    size_t s0 = (size_t)csr[e] * 64 + lane;
    size_t s1 = (size_t)csr[e + 1] * 64 + lane;
    unsigned int u00 = g0[s0], u01 = g1[s0], u02 = g2[s0];
    unsigned int u10 = g0[s1], u11 = g1[s1], u12 = g2[s1];
    float2 v;
    v = h2f2(u00); a0.x += v.x; a0.y += v.y;
    v = h2f2(u01); a1.x += v.x; a1.y += v.y;
    v = h2f2(u02); a2.x += v.x; a2.y += v.y;
    v = h2f2(u10); a0.x += v.x; a0.y += v.y;
    v = h2f2(u11); a1.x += v.x; a1.y += v.y;
    v = h2f2(u12); a2.x += v.x; a2.y += v.y;
  }
  for (; e < end; ++e) {
    size_t s0 = (size_t)csr[e] * 64 + lane;
    float2 v;
    v = h2f2(g0[s0]); a0.x += v.x; a0.y += v.y;
    v = h2f2(g1[s0]); a1.x += v.x; a1.y += v.y;
    v = h2f2(g2[s0]); a2.x += v.x; a2.y += v.y;
  }
  float deg = (float)(cnt[w] + 1);
  spmm_store(o0, base, a0, deg, md0, nullptr);
  spmm_store(o1, base, a1, deg, md1, nullptr);
  spmm_store(o2, base, a2, deg, md2, nullptr);
}

// ---------------- launch ----------------

extern "C" void kernel_launch(void* const* d_in, const int* in_sizes, int n_in,
                              void* d_out, int out_size, void* d_ws, size_t ws_size,
                              hipStream_t stream) {
  const float* x    = (const float*)d_in[0];
  const int*   ei   = (const int*)d_in[1];
  const int*   knn  = (const int*)d_in[2];
  const float* W_s1 = (const float*)d_in[3];
  const float* b_s1 = (const float*)d_in[4];
  const float* W_s2 = (const float*)d_in[5];
  const float* b_s2 = (const float*)d_in[6];
  const float* W_f2 = (const float*)d_in[7];
  const float* b_f2 = (const float*)d_in[8];

  const int N  = in_sizes[0] / F_IN;
  const int E  = in_sizes[1] / 2;
  const int EK = in_sizes[2] / 2;
  const int* row_s = ei;   const int* col_s = ei + E;
  const int* row_k = knn;  const int* col_k = knn + EK;

  char* p = (char*)d_ws;
  auto carve = [&](size_t bytes) {
    char* r = p; p += (bytes + 511) & ~(size_t)511; return (void*)r;
  };
  int* cnt_s = (int*)carve((size_t)N * 4);
  int* cnt_k = (int*)carve((size_t)N * 4);
  int* cur_s = (int*)carve((size_t)N * 4);
  int* cur_k = (int*)carve((size_t)N * 4);
  char* zero_end = p;
  int* offs_s = (int*)carve((size_t)(N + 1) * 4);
  int* offs_k = (int*)carve((size_t)(N + 1) * 4);
  int* bsum   = (int*)carve(4096);
  int* csr_s  = (int*)carve((size_t)E * 4);
  int* csr_k  = (int*)carve((size_t)EK * 4);
  _Float16* Wh  = (_Float16*)carve((size_t)3 * HID * F_IN * 2);
  _Float16* gS1 = (_Float16*)carve((size_t)N * HID * 2);
  _Float16* gS2 = (_Float16*)carve((size_t)N * HID * 2);
  _Float16* gF2s= (_Float16*)carve((size_t)N * HID * 2);
  _Float16* gF2k= (_Float16*)carve((size_t)N * HID * 2);
  _Float16* tS2 = (_Float16*)carve((size_t)N * HID * 2);

  float* out_h0 = (float*)d_out;
  float* out_h1 = out_h0 + (size_t)N * HID;
  float* out_z0 = out_h1 + (size_t)N * HID;
  float* out_z1 = out_z0 + (size_t)N * HID;
  // z1 region (fp32, N*HID floats = 2x fp16 buffers) is free until the very last
  // launch -> scratch for the two single-use step-1 outputs.
  _Float16* tS1 = (_Float16*)out_z1;
  _Float16* tF2 = tS1 + (size_t)N * HID;

  hipMemsetAsync(d_ws, 0, (size_t)(zero_end - (char*)d_ws), stream);

  const int tpb = 256;
  int etot = E + EK;
  k_count2<<<(etot + tpb - 1) / tpb, tpb, 0, stream>>>(col_s, E, cnt_s, col_k, EK, cnt_k);

  int nb = (N + 1023) / 1024;
  k_scan_block<<<nb, 1024, 0, stream>>>(cnt_s, N, offs_s, bsum);
  k_scan_single<<<1, 64, 0, stream>>>(bsum, nb, offs_s + N);
  k_add_off<<<(N + tpb - 1) / tpb, tpb, 0, stream>>>(offs_s, bsum, N);
  k_scan_block<<<nb, 1024, 0, stream>>>(cnt_k, N, offs_k, bsum);
  k_scan_single<<<1, 64, 0, stream>>>(bsum, nb, offs_k + N);
  k_add_off<<<(N + tpb - 1) / tpb, tpb, 0, stream>>>(offs_k, bsum, N);

  k_scatter2<<<(etot + tpb - 1) / tpb, tpb, 0, stream>>>(
      row_s, col_s, E, offs_s, cur_s, csr_s,
      row_k, col_k, EK, offs_k, cur_k, csr_k);

  k_cvt_w<<<96, 256, 0, stream>>>(W_s1, W_s2, W_f2, Wh);
  dim3 ggrid((N + 63) / 64, 3);
  k_gemm3<<<ggrid, 256, 0, stream>>>(x, Wh, b_s1, b_s2, b_f2, N, cnt_s, cnt_k,
                                     gS1, gS2, gF2s, gF2k);

  int spmm_grid = (N + 3) / 4;

  // step 1 (all chains), step 2 (s1 & f2 finalize, s2 continues)
  k_spmm3<<<spmm_grid, 256, 0, stream>>>((const unsigned int*)gS1, (const unsigned int*)gS2,
                                         (const unsigned int*)gF2s,
                                         tS1, tS2, tF2, 0, 0, 0,
                                         csr_s, offs_s, cnt_s, N);
  k_spmm3<<<spmm_grid, 256, 0, stream>>>((const unsigned int*)tS1, (const unsigned int*)tS2,
                                         (const unsigned int*)tF2,
                                         out_h0, gS1, out_z0, 1, 0, 1,
                                         csr_s, offs_s, cnt_s, N);

  // s2 steps 3..10: ping-pong gS1 <-> tS2
  {
    _Float16* cur = gS1; _Float16* alt = tS2;
    for (int it = 0; it < 7; ++it) {
      k_spmm_h<<<spmm_grid, 256, 0, stream>>>((const unsigned int*)cur, alt,
                                              csr_s, offs_s, cnt_s, N, 0, nullptr);
      _Float16* t = cur; cur = alt; alt = t;
    }
    k_spmm_h<<<spmm_grid, 256, 0, stream>>>((const unsigned int*)cur, out_h1,
                                            csr_s, offs_s, cnt_s, N, 1, nullptr);
  }

  // knn step (last: frees the z1 scratch region before writing it)
  k_spmm_h<<<spmm_grid, 256, 0, stream>>>((const unsigned int*)gF2k, out_z1,
                                          csr_k, offs_k, cnt_k, N, 2,
                                          (const float2*)out_z0);
}

// Round 4
// 723.363 us; speedup vs baseline: 1.6367x; 1.0189x over previous
//
#include <hip/hip_runtime.h>
#include <hip/hip_fp16.h>

#define F_IN 256
#define HID 128

typedef _Float16 half8 __attribute__((ext_vector_type(8)));
typedef _Float16 half4v __attribute__((ext_vector_type(4)));
typedef float f32x4 __attribute__((ext_vector_type(4)));

// ---------------- graph preprocessing ----------------

__global__ void k_count2(const int* __restrict__ col_s, int E, int* __restrict__ cnt_s,
                         const int* __restrict__ col_k, int EK, int* __restrict__ cnt_k) {
  int e = blockIdx.x * blockDim.x + threadIdx.x;
  if (e < E) {
    atomicAdd(&cnt_s[col_s[e]], 1);
  } else {
    int f = e - E;
    if (f < EK) atomicAdd(&cnt_k[col_k[f]], 1);
  }
}

__global__ void k_scan_block(const int* __restrict__ in, int n, int* __restrict__ out,
                             int* __restrict__ bsum) {
  __shared__ int s[1024];
  int tid = threadIdx.x;
  int i = blockIdx.x * 1024 + tid;
  int v = (i < n) ? in[i] : 0;
  s[tid] = v;
  __syncthreads();
  for (int off = 1; off < 1024; off <<= 1) {
    int t = (tid >= off) ? s[tid - off] : 0;
    __syncthreads();
    s[tid] += t;
    __syncthreads();
  }
  if (i < n) out[i] = s[tid] - v;          // exclusive
  if (tid == 1023) bsum[blockIdx.x] = s[1023];
}

__global__ void k_scan_single(int* __restrict__ bsum, int nb, int* __restrict__ tail) {
  if (threadIdx.x == 0 && blockIdx.x == 0) {
    int run = 0;
    for (int b = 0; b < nb; ++b) { int t = bsum[b]; bsum[b] = run; run += t; }
    *tail = run;
  }
}

__global__ void k_add_off(int* __restrict__ out, const int* __restrict__ bsum, int n) {
  int i = blockIdx.x * blockDim.x + threadIdx.x;
  if (i < n) out[i] += bsum[i >> 10];
}

__global__ void k_scatter2(const int* __restrict__ row_s, const int* __restrict__ col_s, int E,
                           const int* __restrict__ offs_s, int* __restrict__ cur_s,
                           int* __restrict__ csr_s,
                           const int* __restrict__ row_k, const int* __restrict__ col_k, int EK,
                           const int* __restrict__ offs_k, int* __restrict__ cur_k,
                           int* __restrict__ csr_k) {
  int e = blockIdx.x * blockDim.x + threadIdx.x;
  if (e < E) {
    int c = col_s[e];
    int p = offs_s[c] + atomicAdd(&cur_s[c], 1);
    csr_s[p] = row_s[e];
  } else {
    int f = e - E;
    if (f < EK) {
      int c = col_k[f];
      int p = offs_k[c] + atomicAdd(&cur_k[c], 1);
      csr_k[p] = row_k[f];
    }
  }
}

// ---------------- W fp32 -> fp16 (all three, concatenated) ----------------

__global__ void k_cvt_w(const float* __restrict__ W0, const float* __restrict__ W1,
                        const float* __restrict__ W2, _Float16* __restrict__ Wh) {
  const int sz = HID * F_IN;                    // 32768
  int idx = (blockIdx.x * 256 + threadIdx.x) * 4;  // [0, 3*sz)
  const float* src = (idx < sz) ? (W0 + idx)
                   : (idx < 2 * sz) ? (W1 + idx - sz)
                   : (W2 + idx - 2 * sz);
  float4 v = *(const float4*)src;
  half4v o;
  o[0] = (_Float16)v.x; o[1] = (_Float16)v.y; o[2] = (_Float16)v.z; o[3] = (_Float16)v.w;
  *(half4v*)(Wh + idx) = o;
}

// ---------------- fused MFMA GEMM ----------------
// grid (tiles, 3): blockIdx.y selects the weight matrix; 64 nodes/block, 16/wave.
// kt-OUTER loop with 8 independent accumulators: each x fragment is loaded once
// and the 8 MFMAs per kt are independent -> no residency problem, deep MLP.

__global__ __launch_bounds__(256, 4) void k_gemm3(
    const float* __restrict__ x, const _Float16* __restrict__ Wh,
    const float* __restrict__ b0, const float* __restrict__ b1, const float* __restrict__ b2,
    int n, const int* __restrict__ cnt_s, const int* __restrict__ cnt_k,
    _Float16* __restrict__ gS1, _Float16* __restrict__ gS2,
    _Float16* __restrict__ gF2s, _Float16* __restrict__ gF2k)
{
  int w = blockIdx.y;
  int lane = threadIdx.x & 63;
  int wv = threadIdx.x >> 6;
  int l15 = lane & 15, lhi = lane >> 4;
  int mrow = blockIdx.x * 64 + wv * 16 + l15;
  bool mok = mrow < n;
  int arow = mok ? mrow : (n - 1);

  const float* bias = (w == 0) ? b0 : (w == 1) ? b1 : b2;
  _Float16* dst = (w == 0) ? gS1 : (w == 1) ? gS2 : gF2s;
  const _Float16* Wp = Wh + (size_t)w * HID * F_IN + (size_t)l15 * F_IN + lhi * 8;
  const float* xr = x + (size_t)arow * F_IN + lhi * 8;

  f32x4 acc[8];
#pragma unroll
  for (int nt = 0; nt < 8; ++nt) {
    float4 bv = *(const float4*)(bias + nt * 16 + lhi * 4);
    acc[nt] = (f32x4){bv.x, bv.y, bv.z, bv.w};
  }

#pragma unroll
  for (int kt = 0; kt < 8; ++kt) {
    float4 lo = *(const float4*)(xr + kt * 32);
    float4 hi = *(const float4*)(xr + kt * 32 + 4);
    half8 av;
    av[0] = (_Float16)lo.x; av[1] = (_Float16)lo.y; av[2] = (_Float16)lo.z; av[3] = (_Float16)lo.w;
    av[4] = (_Float16)hi.x; av[5] = (_Float16)hi.y; av[6] = (_Float16)hi.z; av[7] = (_Float16)hi.w;
#pragma unroll
    for (int nt = 0; nt < 8; ++nt) {
      half8 bf = *(const half8*)(Wp + (size_t)nt * 16 * F_IN + kt * 32);
      acc[nt] = __builtin_amdgcn_mfma_f32_16x16x32_f16(bf, av, acc[nt], 0, 0, 0);
    }
  }

  if (mok) {
    float ss = rsqrtf((float)(cnt_s[mrow] + 1));
    float sk = (w == 2) ? rsqrtf((float)(cnt_k[mrow] + 1)) : 0.f;
#pragma unroll
    for (int nt = 0; nt < 8; ++nt) {
      int nbase = nt * 16 + lhi * 4;
      half4v o;
      o[0] = (_Float16)(acc[nt][0] * ss); o[1] = (_Float16)(acc[nt][1] * ss);
      o[2] = (_Float16)(acc[nt][2] * ss); o[3] = (_Float16)(acc[nt][3] * ss);
      *(half4v*)(dst + (size_t)mrow * HID + nbase) = o;
      if (w == 2) {
        half4v o2;
        o2[0] = (_Float16)(acc[nt][0] * sk); o2[1] = (_Float16)(acc[nt][1] * sk);
        o2[2] = (_Float16)(acc[nt][2] * sk); o2[3] = (_Float16)(acc[nt][3] * sk);
        *(half4v*)(gF2k + (size_t)mrow * HID + nbase) = o2;
      }
    }
  }
}

// ---------------- SpMM (fp16 features) ----------------
// g'[i] = scale(i) * (g[i] + sum_src g[src]);  one wave per dest node, 1 dword/lane.
// mode 0: *1/deg -> fp16 out;  mode 1: *rsqrt(deg) -> fp32 out;  mode 2: mode1 + addsrc.

__device__ inline float2 h2f2(unsigned int u) {
  __half2 h; *(unsigned int*)&h = u; return __half22float2(h);
}

__device__ inline void spmm_store(void* out, size_t base, float2 acc, float deg, int mode,
                                  const float2* __restrict__ add) {
  if (mode == 0) {
    float sc = 1.0f / deg;
    __half2 h = __float22half2_rn(make_float2(acc.x * sc, acc.y * sc));
    ((__half2*)out)[base] = h;
  } else {
    float sc = rsqrtf(deg);
    float2 o = make_float2(acc.x * sc, acc.y * sc);
    if (mode == 2) { float2 z = add[base]; o.x += z.x; o.y += z.y; }
    ((float2*)out)[base] = o;
  }
}

__global__ __launch_bounds__(256) void k_spmm_h(
    const unsigned int* __restrict__ gin, void* __restrict__ gout,
    const int* __restrict__ csr, const int* __restrict__ offs, const int* __restrict__ cnt,
    int n, int mode, const float2* __restrict__ addsrc)
{
  int w = (blockIdx.x << 2) | ((int)threadIdx.x >> 6);
  if (w >= n) return;
  int lane = threadIdx.x & 63;
  int beg = offs[w], end = offs[w + 1];
  size_t base = (size_t)w * 64 + lane;
  float2 acc = h2f2(gin[base]);                  // self loop
  int e = beg;
#pragma unroll 1
  for (; e + 16 <= end; e += 16) {
    unsigned int u[16];
#pragma unroll
    for (int j = 0; j < 16; ++j)
      u[j] = gin[((size_t)(unsigned)csr[e + j] << 6) + lane];
    float sx = 0.f, sy = 0.f;
#pragma unroll
    for (int j = 0; j < 16; ++j) { float2 v = h2f2(u[j]); sx += v.x; sy += v.y; }
    acc.x += sx; acc.y += sy;
  }
#pragma unroll 1
  for (; e + 4 <= end; e += 4) {
    unsigned int u[4];
#pragma unroll
    for (int j = 0; j < 4; ++j)
      u[j] = gin[((size_t)(unsigned)csr[e + j] << 6) + lane];
    float sx = 0.f, sy = 0.f;
#pragma unroll
    for (int j = 0; j < 4; ++j) { float2 v = h2f2(u[j]); sx += v.x; sy += v.y; }
    acc.x += sx; acc.y += sy;
  }
  for (; e < end; ++e) {
    float2 v = h2f2(gin[((size_t)(unsigned)csr[e] << 6) + lane]);
    acc.x += v.x; acc.y += v.y;
  }
  spmm_store(gout, base, acc, (float)(cnt[w] + 1), mode, addsrc);
}

// 3 feature matrices propagated in one pass over the graph (shared steps 1,2)
__global__ __launch_bounds__(256) void k_spmm3(
    const unsigned int* __restrict__ g0, const unsigned int* __restrict__ g1,
    const unsigned int* __restrict__ g2,
    void* __restrict__ o0, void* __restrict__ o1, void* __restrict__ o2,
    int md0, int md1, int md2,
    const int* __restrict__ csr, const int* __restrict__ offs, const int* __restrict__ cnt,
    int n)
{
  int w = (blockIdx.x << 2) | ((int)threadIdx.x >> 6);
  if (w >= n) return;
  int lane = threadIdx.x & 63;
  int beg = offs[w], end = offs[w + 1];
  size_t base = (size_t)w * 64 + lane;
  float2 a0 = h2f2(g0[base]), a1 = h2f2(g1[base]), a2 = h2f2(g2[base]);
  int e = beg;
#pragma unroll 1
  for (; e + 4 <= end; e += 4) {
    size_t s[4];
#pragma unroll
    for (int j = 0; j < 4; ++j) s[j] = ((size_t)(unsigned)csr[e + j] << 6) + lane;
    unsigned int u0[4], u1[4], u2[4];
#pragma unroll
    for (int j = 0; j < 4; ++j) { u0[j] = g0[s[j]]; u1[j] = g1[s[j]]; u2[j] = g2[s[j]]; }
#pragma unroll
    for (int j = 0; j < 4; ++j) {
      float2 v;
      v = h2f2(u0[j]); a0.x += v.x; a0.y += v.y;
      v = h2f2(u1[j]); a1.x += v.x; a1.y += v.y;
      v = h2f2(u2[j]); a2.x += v.x; a2.y += v.y;
    }
  }
  for (; e < end; ++e) {
    size_t s0 = ((size_t)(unsigned)csr[e] << 6) + lane;
    float2 v;
    v = h2f2(g0[s0]); a0.x += v.x; a0.y += v.y;
    v = h2f2(g1[s0]); a1.x += v.x; a1.y += v.y;
    v = h2f2(g2[s0]); a2.x += v.x; a2.y += v.y;
  }
  float deg = (float)(cnt[w] + 1);
  spmm_store(o0, base, a0, deg, md0, nullptr);
  spmm_store(o1, base, a1, deg, md1, nullptr);
  spmm_store(o2, base, a2, deg, md2, nullptr);
}

// ---------------- launch ----------------

extern "C" void kernel_launch(void* const* d_in, const int* in_sizes, int n_in,
                              void* d_out, int out_size, void* d_ws, size_t ws_size,
                              hipStream_t stream) {
  const float* x    = (const float*)d_in[0];
  const int*   ei   = (const int*)d_in[1];
  const int*   knn  = (const int*)d_in[2];
  const float* W_s1 = (const float*)d_in[3];
  const float* b_s1 = (const float*)d_in[4];
  const float* W_s2 = (const float*)d_in[5];
  const float* b_s2 = (const float*)d_in[6];
  const float* W_f2 = (const float*)d_in[7];
  const float* b_f2 = (const float*)d_in[8];

  const int N  = in_sizes[0] / F_IN;
  const int E  = in_sizes[1] / 2;
  const int EK = in_sizes[2] / 2;
  const int* row_s = ei;   const int* col_s = ei + E;
  const int* row_k = knn;  const int* col_k = knn + EK;

  char* p = (char*)d_ws;
  auto carve = [&](size_t bytes) {
    char* r = p; p += (bytes + 511) & ~(size_t)511; return (void*)r;
  };
  int* cnt_s = (int*)carve((size_t)N * 4);
  int* cnt_k = (int*)carve((size_t)N * 4);
  int* cur_s = (int*)carve((size_t)N * 4);
  int* cur_k = (int*)carve((size_t)N * 4);
  char* zero_end = p;
  int* offs_s = (int*)carve((size_t)(N + 1) * 4);
  int* offs_k = (int*)carve((size_t)(N + 1) * 4);
  int* bsum   = (int*)carve(4096);
  int* csr_s  = (int*)carve((size_t)E * 4);
  int* csr_k  = (int*)carve((size_t)EK * 4);
  _Float16* Wh  = (_Float16*)carve((size_t)3 * HID * F_IN * 2);
  _Float16* gS1 = (_Float16*)carve((size_t)N * HID * 2);
  _Float16* gS2 = (_Float16*)carve((size_t)N * HID * 2);
  _Float16* gF2s= (_Float16*)carve((size_t)N * HID * 2);
  _Float16* gF2k= (_Float16*)carve((size_t)N * HID * 2);
  _Float16* tS2 = (_Float16*)carve((size_t)N * HID * 2);

  float* out_h0 = (float*)d_out;
  float* out_h1 = out_h0 + (size_t)N * HID;
  float* out_z0 = out_h1 + (size_t)N * HID;
  float* out_z1 = out_z0 + (size_t)N * HID;
  // z1 region (fp32, N*HID floats = 2x fp16 buffers) is free until the very last
  // launch -> scratch for the two single-use step-1 outputs.
  _Float16* tS1 = (_Float16*)out_z1;
  _Float16* tF2 = tS1 + (size_t)N * HID;

  hipMemsetAsync(d_ws, 0, (size_t)(zero_end - (char*)d_ws), stream);

  const int tpb = 256;
  int etot = E + EK;
  k_count2<<<(etot + tpb - 1) / tpb, tpb, 0, stream>>>(col_s, E, cnt_s, col_k, EK, cnt_k);

  int nb = (N + 1023) / 1024;
  k_scan_block<<<nb, 1024, 0, stream>>>(cnt_s, N, offs_s, bsum);
  k_scan_single<<<1, 64, 0, stream>>>(bsum, nb, offs_s + N);
  k_add_off<<<(N + tpb - 1) / tpb, tpb, 0, stream>>>(offs_s, bsum, N);
  k_scan_block<<<nb, 1024, 0, stream>>>(cnt_k, N, offs_k, bsum);
  k_scan_single<<<1, 64, 0, stream>>>(bsum, nb, offs_k + N);
  k_add_off<<<(N + tpb - 1) / tpb, tpb, 0, stream>>>(offs_k, bsum, N);

  k_scatter2<<<(etot + tpb - 1) / tpb, tpb, 0, stream>>>(
      row_s, col_s, E, offs_s, cur_s, csr_s,
      row_k, col_k, EK, offs_k, cur_k, csr_k);

  k_cvt_w<<<96, 256, 0, stream>>>(W_s1, W_s2, W_f2, Wh);
  dim3 ggrid((N + 63) / 64, 3);
  k_gemm3<<<ggrid, 256, 0, stream>>>(x, Wh, b_s1, b_s2, b_f2, N, cnt_s, cnt_k,
                                     gS1, gS2, gF2s, gF2k);

  int spmm_grid = (N + 3) / 4;

  // step 1 (all chains), step 2 (s1 & f2 finalize, s2 continues)
  k_spmm3<<<spmm_grid, 256, 0, stream>>>((const unsigned int*)gS1, (const unsigned int*)gS2,
                                         (const unsigned int*)gF2s,
                                         tS1, tS2, tF2, 0, 0, 0,
                                         csr_s, offs_s, cnt_s, N);
  k_spmm3<<<spmm_grid, 256, 0, stream>>>((const unsigned int*)tS1, (const unsigned int*)tS2,
                                         (const unsigned int*)tF2,
                                         out_h0, gS1, out_z0, 1, 0, 1,
                                         csr_s, offs_s, cnt_s, N);

  // s2 steps 3..10: ping-pong gS1 <-> tS2
  {
    _Float16* cur = gS1; _Float16* alt = tS2;
    for (int it = 0; it < 7; ++it) {
      k_spmm_h<<<spmm_grid, 256, 0, stream>>>((const unsigned int*)cur, alt,
                                              csr_s, offs_s, cnt_s, N, 0, nullptr);
      _Float16* t = cur; cur = alt; alt = t;
    }
    k_spmm_h<<<spmm_grid, 256, 0, stream>>>((const unsigned int*)cur, out_h1,
                                            csr_s, offs_s, cnt_s, N, 1, nullptr);
  }

  // knn step (last: frees the z1 scratch region before writing it)
  k_spmm_h<<<spmm_grid, 256, 0, stream>>>((const unsigned int*)gF2k, out_z1,
                                          csr_k, offs_k, cnt_k, N, 2,
                                          (const float2*)out_z0);
}

// Round 5
// 719.650 us; speedup vs baseline: 1.6452x; 1.0052x over previous
//
#include <hip/hip_runtime.h>
#include <hip/hip_fp16.h>

#define F_IN 256
#define HID 128

typedef _Float16 half8 __attribute__((ext_vector_type(8)));
typedef _Float16 half4v __attribute__((ext_vector_type(4)));
typedef float f32x4 __attribute__((ext_vector_type(4)));

// ---------------- graph preprocessing ----------------

__global__ void k_count2(const int* __restrict__ col_s, int E, int* __restrict__ cnt_s,
                         const int* __restrict__ col_k, int EK, int* __restrict__ cnt_k) {
  int e = blockIdx.x * blockDim.x + threadIdx.x;
  if (e < E) {
    atomicAdd(&cnt_s[col_s[e]], 1);
  } else {
    int f = e - E;
    if (f < EK) atomicAdd(&cnt_k[col_k[f]], 1);
  }
}

__global__ void k_scan_block(const int* __restrict__ in, int n, int* __restrict__ out,
                             int* __restrict__ bsum) {
  __shared__ int s[1024];
  int tid = threadIdx.x;
  int i = blockIdx.x * 1024 + tid;
  int v = (i < n) ? in[i] : 0;
  s[tid] = v;
  __syncthreads();
  for (int off = 1; off < 1024; off <<= 1) {
    int t = (tid >= off) ? s[tid - off] : 0;
    __syncthreads();
    s[tid] += t;
    __syncthreads();
  }
  if (i < n) out[i] = s[tid] - v;          // exclusive
  if (tid == 1023) bsum[blockIdx.x] = s[1023];
}

__global__ void k_scan_single(int* __restrict__ bsum, int nb, int* __restrict__ tail) {
  if (threadIdx.x == 0 && blockIdx.x == 0) {
    int run = 0;
    for (int b = 0; b < nb; ++b) { int t = bsum[b]; bsum[b] = run; run += t; }
    *tail = run;
  }
}

__global__ void k_add_off(int* __restrict__ out, const int* __restrict__ bsum, int n) {
  int i = blockIdx.x * blockDim.x + threadIdx.x;
  if (i < n) out[i] += bsum[i >> 10];
}

__global__ void k_scatter2(const int* __restrict__ row_s, const int* __restrict__ col_s, int E,
                           const int* __restrict__ offs_s, int* __restrict__ cur_s,
                           int* __restrict__ csr_s,
                           const int* __restrict__ row_k, const int* __restrict__ col_k, int EK,
                           const int* __restrict__ offs_k, int* __restrict__ cur_k,
                           int* __restrict__ csr_k) {
  int e = blockIdx.x * blockDim.x + threadIdx.x;
  if (e < E) {
    int c = col_s[e];
    int p = offs_s[c] + atomicAdd(&cur_s[c], 1);
    csr_s[p] = row_s[e];
  } else {
    int f = e - E;
    if (f < EK) {
      int c = col_k[f];
      int p = offs_k[c] + atomicAdd(&cur_k[c], 1);
      csr_k[p] = row_k[f];
    }
  }
}

// ---------------- W fp32 -> fp16 (all three, concatenated) ----------------

__global__ void k_cvt_w(const float* __restrict__ W0, const float* __restrict__ W1,
                        const float* __restrict__ W2, _Float16* __restrict__ Wh) {
  const int sz = HID * F_IN;                    // 32768
  int idx = (blockIdx.x * 256 + threadIdx.x) * 4;  // [0, 3*sz)
  const float* src = (idx < sz) ? (W0 + idx)
                   : (idx < 2 * sz) ? (W1 + idx - sz)
                   : (W2 + idx - 2 * sz);
  float4 v = *(const float4*)src;
  half4v o;
  o[0] = (_Float16)v.x; o[1] = (_Float16)v.y; o[2] = (_Float16)v.z; o[3] = (_Float16)v.w;
  *(half4v*)(Wh + idx) = o;
}

// ---------------- fused MFMA GEMM, LDS-tiled ----------------
// One block = 64 nodes. x tile staged fp32->fp16 into LDS ONCE (XOR-swizzled),
// then the 3 weight slices are computed inside the block (x read once from HBM).
// Wave wv owns all 64 nodes x 32 cols: acc[m=4][n=2] f32x4, ds_read x frags,
// W streamed from L2.

__global__ __launch_bounds__(256, 4) void k_gemm3(
    const float* __restrict__ x, const _Float16* __restrict__ Wh,
    const float* __restrict__ b0, const float* __restrict__ b1, const float* __restrict__ b2,
    int n, const int* __restrict__ cnt_s, const int* __restrict__ cnt_k,
    _Float16* __restrict__ gS1, _Float16* __restrict__ gS2,
    _Float16* __restrict__ gF2s, _Float16* __restrict__ gF2k)
{
  __shared__ _Float16 xs[64 * F_IN];       // 32 KB, swizzled
  int tid = threadIdx.x;
  int m0 = blockIdx.x * 64;

  // ---- stage x tile: thread t -> row t>>2, cols [(t&3)*64, +64) ----
  {
    int r = tid >> 2;
    int cbase = (tid & 3) * 64;
    int gr = m0 + r; if (gr >= n) gr = n - 1;
    const float* src = x + (size_t)gr * F_IN + cbase;
    unsigned sw = (unsigned)((r & 7) << 4);
    char* drow = (char*)xs + r * (F_IN * 2) + cbase * 2;
#pragma unroll
    for (int i = 0; i < 8; ++i) {          // 8 x 16B blocks = 64 fp16
      float4 a = *(const float4*)(src + i * 8);
      float4 b = *(const float4*)(src + i * 8 + 4);
      half8 v;
      v[0] = (_Float16)a.x; v[1] = (_Float16)a.y; v[2] = (_Float16)a.z; v[3] = (_Float16)a.w;
      v[4] = (_Float16)b.x; v[5] = (_Float16)b.y; v[6] = (_Float16)b.z; v[7] = (_Float16)b.w;
      *(half8*)(drow + (((unsigned)(i * 16)) ^ sw)) = v;
    }
  }
  __syncthreads();

  int lane = tid & 63;
  int wv = tid >> 6;                        // col base wv*32
  int l15 = lane & 15, lhi = lane >> 4;
  unsigned swr = (unsigned)((l15 & 7) << 4);

  // per-node scales (independent of weight slice)
  float ss[4], sk[4];
  int nodes[4];
#pragma unroll
  for (int m = 0; m < 4; ++m) {
    int node = m0 + m * 16 + l15;
    nodes[m] = node;
    int cn = (node < n) ? node : (n - 1);
    ss[m] = rsqrtf((float)(cnt_s[cn] + 1));
    sk[m] = rsqrtf((float)(cnt_k[cn] + 1));
  }

  for (int w = 0; w < 3; ++w) {
    const float* bias = (w == 0) ? b0 : (w == 1) ? b1 : b2;
    _Float16* dst = (w == 0) ? gS1 : (w == 1) ? gS2 : gF2s;
    const _Float16* Wp = Wh + (size_t)w * HID * F_IN
                            + (size_t)(wv * 32 + l15) * F_IN + lhi * 8;

    f32x4 acc[4][2];
#pragma unroll
    for (int n2 = 0; n2 < 2; ++n2) {
      float4 bv = *(const float4*)(bias + wv * 32 + n2 * 16 + lhi * 4);
      f32x4 b4 = {bv.x, bv.y, bv.z, bv.w};
#pragma unroll
      for (int m = 0; m < 4; ++m) acc[m][n2] = b4;
    }

#pragma unroll
    for (int kt = 0; kt < 8; ++kt) {
      half8 wf[2];
#pragma unroll
      for (int n2 = 0; n2 < 2; ++n2)
        wf[n2] = *(const half8*)(Wp + (size_t)n2 * 16 * F_IN + kt * 32);
      half8 xf[4];
      unsigned coff = ((unsigned)((lhi * 8 + kt * 32) * 2)) ^ swr;
#pragma unroll
      for (int m = 0; m < 4; ++m)
        xf[m] = *(const half8*)((const char*)xs + (m * 16 + l15) * (F_IN * 2) + coff);
#pragma unroll
      for (int m = 0; m < 4; ++m)
#pragma unroll
        for (int n2 = 0; n2 < 2; ++n2)
          acc[m][n2] = __builtin_amdgcn_mfma_f32_16x16x32_f16(wf[n2], xf[m], acc[m][n2], 0, 0, 0);
    }

#pragma unroll
    for (int m = 0; m < 4; ++m) {
      if (nodes[m] >= n) continue;
      size_t obase = (size_t)nodes[m] * HID + wv * 32 + lhi * 4;
#pragma unroll
      for (int n2 = 0; n2 < 2; ++n2) {
        half4v o;
        o[0] = (_Float16)(acc[m][n2][0] * ss[m]); o[1] = (_Float16)(acc[m][n2][1] * ss[m]);
        o[2] = (_Float16)(acc[m][n2][2] * ss[m]); o[3] = (_Float16)(acc[m][n2][3] * ss[m]);
        *(half4v*)(dst + obase + n2 * 16) = o;
        if (w == 2) {
          half4v o2;
          o2[0] = (_Float16)(acc[m][n2][0] * sk[m]); o2[1] = (_Float16)(acc[m][n2][1] * sk[m]);
          o2[2] = (_Float16)(acc[m][n2][2] * sk[m]); o2[3] = (_Float16)(acc[m][n2][3] * sk[m]);
          *(half4v*)(gF2k + obase + n2 * 16) = o2;
        }
      }
    }
  }
}

// ---------------- SpMM (fp16 features) ----------------
// g'[i] = scale(i) * (g[i] + sum_src g[src]);  one wave per dest node, 1 dword/lane.
// mode 0: *1/deg -> fp16 out;  mode 1: *rsqrt(deg) -> fp32 out;  mode 2: mode1 + addsrc.

__device__ inline float2 h2f2(unsigned int u) {
  __half2 h; *(unsigned int*)&h = u; return __half22float2(h);
}

__device__ inline void spmm_store(void* out, size_t base, float2 acc, float deg, int mode,
                                  const float2* __restrict__ add) {
  if (mode == 0) {
    float sc = 1.0f / deg;
    __half2 h = __float22half2_rn(make_float2(acc.x * sc, acc.y * sc));
    ((__half2*)out)[base] = h;
  } else {
    float sc = rsqrtf(deg);
    float2 o = make_float2(acc.x * sc, acc.y * sc);
    if (mode == 2) { float2 z = add[base]; o.x += z.x; o.y += z.y; }
    ((float2*)out)[base] = o;
  }
}

__global__ __launch_bounds__(256) void k_spmm_h(
    const unsigned int* __restrict__ gin, void* __restrict__ gout,
    const int* __restrict__ csr, const int* __restrict__ offs, const int* __restrict__ cnt,
    int n, int mode, const float2* __restrict__ addsrc)
{
  int w = (blockIdx.x << 2) | ((int)threadIdx.x >> 6);
  if (w >= n) return;
  int lane = threadIdx.x & 63;
  int beg = offs[w], end = offs[w + 1];
  size_t base = (size_t)w * 64 + lane;
  float2 acc = h2f2(gin[base]);                  // self loop
  int e = beg;
#pragma unroll 1
  for (; e + 16 <= end; e += 16) {
    unsigned int u[16];
#pragma unroll
    for (int j = 0; j < 16; ++j)
      u[j] = gin[((size_t)(unsigned)csr[e + j] << 6) + lane];
    float sx = 0.f, sy = 0.f;
#pragma unroll
    for (int j = 0; j < 16; ++j) { float2 v = h2f2(u[j]); sx += v.x; sy += v.y; }
    acc.x += sx; acc.y += sy;
  }
#pragma unroll 1
  for (; e + 4 <= end; e += 4) {
    unsigned int u[4];
#pragma unroll
    for (int j = 0; j < 4; ++j)
      u[j] = gin[((size_t)(unsigned)csr[e + j] << 6) + lane];
    float sx = 0.f, sy = 0.f;
#pragma unroll
    for (int j = 0; j < 4; ++j) { float2 v = h2f2(u[j]); sx += v.x; sy += v.y; }
    acc.x += sx; acc.y += sy;
  }
  for (; e < end; ++e) {
    float2 v = h2f2(gin[((size_t)(unsigned)csr[e] << 6) + lane]);
    acc.x += v.x; acc.y += v.y;
  }
  spmm_store(gout, base, acc, (float)(cnt[w] + 1), mode, addsrc);
}

// 3 feature matrices propagated in one pass over the graph (shared steps 1,2)
__global__ __launch_bounds__(256) void k_spmm3(
    const unsigned int* __restrict__ g0, const unsigned int* __restrict__ g1,
    const unsigned int* __restrict__ g2,
    void* __restrict__ o0, void* __restrict__ o1, void* __restrict__ o2,
    int md0, int md1, int md2,
    const int* __restrict__ csr, const int* __restrict__ offs, const int* __restrict__ cnt,
    int n)
{
  int w = (blockIdx.x << 2) | ((int)threadIdx.x >> 6);
  if (w >= n) return;
  int lane = threadIdx.x & 63;
  int beg = offs[w], end = offs[w + 1];
  size_t base = (size_t)w * 64 + lane;
  float2 a0 = h2f2(g0[base]), a1 = h2f2(g1[base]), a2 = h2f2(g2[base]);
  int e = beg;
#pragma unroll 1
  for (; e + 4 <= end; e += 4) {
    size_t s[4];
#pragma unroll
    for (int j = 0; j < 4; ++j) s[j] = ((size_t)(unsigned)csr[e + j] << 6) + lane;
    unsigned int u0[4], u1[4], u2[4];
#pragma unroll
    for (int j = 0; j < 4; ++j) { u0[j] = g0[s[j]]; u1[j] = g1[s[j]]; u2[j] = g2[s[j]]; }
#pragma unroll
    for (int j = 0; j < 4; ++j) {
      float2 v;
      v = h2f2(u0[j]); a0.x += v.x; a0.y += v.y;
      v = h2f2(u1[j]); a1.x += v.x; a1.y += v.y;
      v = h2f2(u2[j]); a2.x += v.x; a2.y += v.y;
    }
  }
  for (; e < end; ++e) {
    size_t s0 = ((size_t)(unsigned)csr[e] << 6) + lane;
    float2 v;
    v = h2f2(g0[s0]); a0.x += v.x; a0.y += v.y;
    v = h2f2(g1[s0]); a1.x += v.x; a1.y += v.y;
    v = h2f2(g2[s0]); a2.x += v.x; a2.y += v.y;
  }
  float deg = (float)(cnt[w] + 1);
  spmm_store(o0, base, a0, deg, md0, nullptr);
  spmm_store(o1, base, a1, deg, md1, nullptr);
  spmm_store(o2, base, a2, deg, md2, nullptr);
}

// ---------------- launch ----------------

extern "C" void kernel_launch(void* const* d_in, const int* in_sizes, int n_in,
                              void* d_out, int out_size, void* d_ws, size_t ws_size,
                              hipStream_t stream) {
  const float* x    = (const float*)d_in[0];
  const int*   ei   = (const int*)d_in[1];
  const int*   knn  = (const int*)d_in[2];
  const float* W_s1 = (const float*)d_in[3];
  const float* b_s1 = (const float*)d_in[4];
  const float* W_s2 = (const float*)d_in[5];
  const float* b_s2 = (const float*)d_in[6];
  const float* W_f2 = (const float*)d_in[7];
  const float* b_f2 = (const float*)d_in[8];

  const int N  = in_sizes[0] / F_IN;
  const int E  = in_sizes[1] / 2;
  const int EK = in_sizes[2] / 2;
  const int* row_s = ei;   const int* col_s = ei + E;
  const int* row_k = knn;  const int* col_k = knn + EK;

  char* p = (char*)d_ws;
  auto carve = [&](size_t bytes) {
    char* r = p; p += (bytes + 511) & ~(size_t)511; return (void*)r;
  };
  int* cnt_s = (int*)carve((size_t)N * 4);
  int* cnt_k = (int*)carve((size_t)N * 4);
  int* cur_s = (int*)carve((size_t)N * 4);
  int* cur_k = (int*)carve((size_t)N * 4);
  char* zero_end = p;
  int* offs_s = (int*)carve((size_t)(N + 1) * 4);
  int* offs_k = (int*)carve((size_t)(N + 1) * 4);
  int* bsum   = (int*)carve(4096);
  int* csr_s  = (int*)carve((size_t)E * 4);
  int* csr_k  = (int*)carve((size_t)EK * 4);
  _Float16* Wh  = (_Float16*)carve((size_t)3 * HID * F_IN * 2);
  _Float16* gS1 = (_Float16*)carve((size_t)N * HID * 2);
  _Float16* gS2 = (_Float16*)carve((size_t)N * HID * 2);
  _Float16* gF2s= (_Float16*)carve((size_t)N * HID * 2);
  _Float16* gF2k= (_Float16*)carve((size_t)N * HID * 2);
  _Float16* tS2 = (_Float16*)carve((size_t)N * HID * 2);

  float* out_h0 = (float*)d_out;
  float* out_h1 = out_h0 + (size_t)N * HID;
  float* out_z0 = out_h1 + (size_t)N * HID;
  float* out_z1 = out_z0 + (size_t)N * HID;
  // z1 region (fp32, N*HID floats = 2x fp16 buffers) is free until the very last
  // launch -> scratch for the two single-use step-1 outputs.
  _Float16* tS1 = (_Float16*)out_z1;
  _Float16* tF2 = tS1 + (size_t)N * HID;

  hipMemsetAsync(d_ws, 0, (size_t)(zero_end - (char*)d_ws), stream);

  const int tpb = 256;
  int etot = E + EK;
  k_count2<<<(etot + tpb - 1) / tpb, tpb, 0, stream>>>(col_s, E, cnt_s, col_k, EK, cnt_k);

  int nb = (N + 1023) / 1024;
  k_scan_block<<<nb, 1024, 0, stream>>>(cnt_s, N, offs_s, bsum);
  k_scan_single<<<1, 64, 0, stream>>>(bsum, nb, offs_s + N);
  k_add_off<<<(N + tpb - 1) / tpb, tpb, 0, stream>>>(offs_s, bsum, N);
  k_scan_block<<<nb, 1024, 0, stream>>>(cnt_k, N, offs_k, bsum);
  k_scan_single<<<1, 64, 0, stream>>>(bsum, nb, offs_k + N);
  k_add_off<<<(N + tpb - 1) / tpb, tpb, 0, stream>>>(offs_k, bsum, N);

  k_scatter2<<<(etot + tpb - 1) / tpb, tpb, 0, stream>>>(
      row_s, col_s, E, offs_s, cur_s, csr_s,
      row_k, col_k, EK, offs_k, cur_k, csr_k);

  k_cvt_w<<<96, 256, 0, stream>>>(W_s1, W_s2, W_f2, Wh);
  k_gemm3<<<(N + 63) / 64, 256, 0, stream>>>(x, Wh, b_s1, b_s2, b_f2, N, cnt_s, cnt_k,
                                             gS1, gS2, gF2s, gF2k);

  int spmm_grid = (N + 3) / 4;

  // step 1 (all chains), step 2 (s1 & f2 finalize, s2 continues)
  k_spmm3<<<spmm_grid, 256, 0, stream>>>((const unsigned int*)gS1, (const unsigned int*)gS2,
                                         (const unsigned int*)gF2s,
                                         tS1, tS2, tF2, 0, 0, 0,
                                         csr_s, offs_s, cnt_s, N);
  k_spmm3<<<spmm_grid, 256, 0, stream>>>((const unsigned int*)tS1, (const unsigned int*)tS2,
                                         (const unsigned int*)tF2,
                                         out_h0, gS1, out_z0, 1, 0, 1,
                                         csr_s, offs_s, cnt_s, N);

  // s2 steps 3..10: ping-pong gS1 <-> tS2
  {
    _Float16* cur = gS1; _Float16* alt = tS2;
    for (int it = 0; it < 7; ++it) {
      k_spmm_h<<<spmm_grid, 256, 0, stream>>>((const unsigned int*)cur, alt,
                                              csr_s, offs_s, cnt_s, N, 0, nullptr);
      _Float16* t = cur; cur = alt; alt = t;
    }
    k_spmm_h<<<spmm_grid, 256, 0, stream>>>((const unsigned int*)cur, out_h1,
                                            csr_s, offs_s, cnt_s, N, 1, nullptr);
  }

  // knn step (last: frees the z1 scratch region before writing it)
  k_spmm_h<<<spmm_grid, 256, 0, stream>>>((const unsigned int*)gF2k, out_z1,
                                          csr_k, offs_k, cnt_k, N, 2,
                                          (const float2*)out_z0);
}